// Round 7
// baseline (250.267 us; speedup 1.0000x reference)
//
#include <hip/hip_runtime.h>

#define NB 16
#define HH 512
#define WW 512
#define HWN (HH * WW)            // 262144 = 1<<18
#define SENT HWN                  // background sentinel
#define KC 512                    // max regions kept per image
#define RCAP 4096                 // root list capacity per image
#define CCAP 4096                 // tile-root slot capacity per image
#define PN (NB * HWN)
#define TPB 256
#define IMAX 0x7FFFFFFF
#define TS 64                     // CCL tile side
#define TSQ (TS * TS)             // 4096, local sentinel

// ---------------- union-find helpers (global mem) ----------------
__device__ __forceinline__ int findRoot(int* L, int i) {
    int p = L[i];
    while (p != i) { i = p; p = L[i]; }
    return i;
}

__device__ __forceinline__ int chaseRoot(const int* __restrict__ L, int i) {
    int p = L[i];
    while (p != i) { i = p; p = L[i]; }
    return i;
}

__device__ __forceinline__ void unite(int* L, int a, int b) {
    int ra = findRoot(L, a);
    int rb = findRoot(L, b);
    while (ra != rb) {
        int lo = min(ra, rb), hi = max(ra, rb);
        int old = atomicMin(&L[hi], lo);
        if (old == hi) return;
        ra = old; rb = lo;
    }
}

// ---------------- union-find helpers (LDS) ----------------
__device__ __forceinline__ int findRootL(int* s, int i) {
    int p = s[i];
    while (p != i) { i = p; p = s[i]; }
    return i;
}

__device__ __forceinline__ void uniteL(int* s, int a, int b) {
    int ra = findRootL(s, a);
    int rb = findRootL(s, b);
    while (ra != rb) {
        int lo = min(ra, rb), hi = max(ra, rb);
        int old = atomicMin(&s[hi], lo);
        if (old == hi) return;
        ra = old; rb = lo;
    }
}

// binary search exact key in ascending array of KC ints (padded IMAX)
__device__ __forceinline__ int bsearch_k(const int* a, int key) {
    int lo = 0, hi = KC;
    while (lo < hi) { int m = (lo + hi) >> 1; if (a[m] < key) lo = m + 1; else hi = m; }
    return (lo < KC && a[lo] == key) ? lo : -1;
}

// ---------------- kernels ----------------
// Per-tile CCL: run-based labels (ballot), reduced union rules, all in LDS.
// Run-start lanes chase the forest once per RUN (negative slot markers
// terminate); (root,slot) broadcast to the run via shfl. Per-pixel packed
// slot write; labels only for root + tile-edge pixels; run-level stats.
__global__ __launch_bounds__(TPB) void k_local(const float* __restrict__ in, const float* __restrict__ tg,
                        int* __restrict__ labP, int* __restrict__ labG,
                        int* __restrict__ slotPacked,
                        int* __restrict__ candP, int* __restrict__ candG,
                        int* __restrict__ candCntP, int* __restrict__ candCntG,
                        int* __restrict__ sAreaP, int* __restrict__ sRP, int* __restrict__ sCP, int* __restrict__ sOvP,
                        int* __restrict__ sAreaG, int* __restrict__ sRG, int* __restrict__ sCG, int* __restrict__ sOvG) {
    __shared__ int sp[TSQ];
    __shared__ int sg[TSQ];
    __shared__ unsigned long long rmP[TS], rmG[TS];
    __shared__ int anyP, anyG;
    int b = blockIdx.x >> 6;            // 64 tiles per image (8x8)
    int tile = blockIdx.x & 63;
    int r0 = (tile >> 3) << 6, c0 = (tile & 7) << 6;
    int base = (b << 18) + (r0 << 9) + c0;
    int wv = threadIdx.x >> 6, lane = threadIdx.x & 63;
    if (threadIdx.x == 0) { anyP = 0; anyG = 0; }
    __syncthreads();

    // phase 1: load, ballot row masks, run-start labels (fg only, no atomics)
    #pragma unroll
    for (int k = 0; k < 16; k++) {
        int lr = wv + (k << 2);
        bool p = in[base + (lr << 9) + lane] > 0.0f;   // sigmoid(x)>0.5 <=> x>0
        bool q = tg[base + (lr << 9) + lane] > 0.5f;
        unsigned long long mp = __ballot(p);
        unsigned long long mq = __ballot(q);
        int t = (lr << 6) + lane;
        if (p) {
            unsigned long long below = (lane == 0) ? 0ULL : ((~mp) & ((1ULL << lane) - 1ULL));
            int st = below ? (64 - __clzll(below)) : 0;
            sp[t] = (lr << 6) + st;
        }
        if (q) {
            unsigned long long below = (lane == 0) ? 0ULL : ((~mq) & ((1ULL << lane) - 1ULL));
            int st = below ? (64 - __clzll(below)) : 0;
            sg[t] = (lr << 6) + st;
        }
        if (lane == 0) {
            rmP[lr] = mp; rmG[lr] = mq;
            if (mp) anyP = 1;           // benign WAW race, same value
            if (mq) anyG = 1;
        }
    }
    __syncthreads();
    int aP = anyP, aG = anyG;

    // phase 2: inter-row unions, reduced rules (one union per adjacent run-pair)
    for (int lr = wv; lr < TS; lr += 4) {
        if (lr == 0) continue;
        int t = (lr << 6) + lane;
        if (aP) {
            unsigned long long m = rmP[lr], a = rmP[lr - 1];
            if ((m >> lane) & 1ULL) {
                bool N  = (a >> lane) & 1ULL;
                bool W  = lane > 0  && ((m >> (lane - 1)) & 1ULL);
                bool NW = lane > 0  && ((a >> (lane - 1)) & 1ULL);
                bool E  = lane < 63 && ((m >> (lane + 1)) & 1ULL);
                bool NE = lane < 63 && ((a >> (lane + 1)) & 1ULL);
                if (N) { if (!(W && NW)) uniteL(sp, t, t - TS); }
                else {
                    if (NW && !W) uniteL(sp, t, t - TS - 1);
                    if (NE && !E) uniteL(sp, t, t - TS + 1);
                }
            }
        }
        if (aG) {
            unsigned long long m = rmG[lr], a = rmG[lr - 1];
            if ((m >> lane) & 1ULL) {
                bool N  = (a >> lane) & 1ULL;
                bool W  = lane > 0  && ((m >> (lane - 1)) & 1ULL);
                bool NW = lane > 0  && ((a >> (lane - 1)) & 1ULL);
                bool E  = lane < 63 && ((m >> (lane + 1)) & 1ULL);
                bool NE = lane < 63 && ((a >> (lane + 1)) & 1ULL);
                if (N) { if (!(W && NW)) uniteL(sg, t, t - TS); }
                else {
                    if (NW && !W) uniteL(sg, t, t - TS - 1);
                    if (NE && !E) uniteL(sg, t, t - TS + 1);
                }
            }
        }
    }
    __syncthreads();

    // phase 3b: roots -> slots (encode negative), candidates, root labels
    #pragma unroll
    for (int k = 0; k < 16; k++) {
        int lr = wv + (k << 2);
        int t = (lr << 6) + lane;
        if (aP && ((rmP[lr] >> lane) & 1ULL) && sp[t] == t) {
            int pos = atomicAdd(&candCntP[b], 1);
            if (pos >= CCAP) pos = CCAP - 1;
            int gl = ((r0 + lr) << 9) + (c0 + lane);
            candP[b * CCAP + pos] = gl;
            labP[(b << 18) + gl] = gl;
            sp[t] = -(pos + 2);
        }
        if (aG && ((rmG[lr] >> lane) & 1ULL) && sg[t] == t) {
            int pos = atomicAdd(&candCntG[b], 1);
            if (pos >= CCAP) pos = CCAP - 1;
            int gl = ((r0 + lr) << 9) + (c0 + lane);
            candG[b * CCAP + pos] = gl;
            labG[(b << 18) + gl] = gl;
            sg[t] = -(pos + 2);
        }
    }
    __syncthreads();

    // phase 3c: run-start chase + shfl broadcast; packed slot write;
    // edge labels; run stats.
    for (int k = 0; k < 16; k++) {
        int lr = wv + (k << 2);
        int g = base + (lr << 9) + lane;
        unsigned long long mp = aP ? rmP[lr] : 0ULL;
        unsigned long long mq = aG ? rmG[lr] : 0ULL;
        bool fgP = (mp >> lane) & 1ULL;
        bool fgG = (mq >> lane) & 1ULL;
        unsigned long long belowP = (lane == 0) ? 0ULL : ((~mp) & ((1ULL << lane) - 1ULL));
        int stP = belowP ? (64 - __clzll(belowP)) : 0;
        unsigned long long belowG = (lane == 0) ? 0ULL : ((~mq) & ((1ULL << lane) - 1ULL));
        int stG = belowG ? (64 - __clzll(belowG)) : 0;
        int rootP = 0, posP = 0;
        if (fgP && lane == stP) {
            int i = (lr << 6) + lane;
            int pp = sp[i];
            while (pp >= 0) { i = pp; pp = sp[i]; }
            rootP = i; posP = -pp - 2;
            unsigned long long x = ~(mp >> lane);
            int len = x ? (__ffsll((long long)x) - 1) : (64 - lane);
            unsigned long long runbits = (len >= 64) ? ~0ULL : (((1ULL << len) - 1ULL) << lane);
            atomicAdd(&sAreaP[b * CCAP + posP], len);
            atomicAdd(&sRP[b * CCAP + posP], (r0 + lr) * len);
            atomicAdd(&sCP[b * CCAP + posP], len * (c0 + lane) + (len * (len - 1)) / 2);
            if (mq & runbits) atomicOr(&sOvP[b * CCAP + posP], 1);
        }
        int rootG = 0, posG = 0;
        if (fgG && lane == stG) {
            int i = (lr << 6) + lane;
            int pp = sg[i];
            while (pp >= 0) { i = pp; pp = sg[i]; }
            rootG = i; posG = -pp - 2;
            unsigned long long x = ~(mq >> lane);
            int len = x ? (__ffsll((long long)x) - 1) : (64 - lane);
            unsigned long long runbits = (len >= 64) ? ~0ULL : (((1ULL << len) - 1ULL) << lane);
            atomicAdd(&sAreaG[b * CCAP + posG], len);
            atomicAdd(&sRG[b * CCAP + posG], (r0 + lr) * len);
            atomicAdd(&sCG[b * CCAP + posG], len * (c0 + lane) + (len * (len - 1)) / 2);
            if (mp & runbits) atomicOr(&sOvG[b * CCAP + posG], 1);
        }
        rootP = __shfl(rootP, stP); posP = __shfl(posP, stP);
        rootG = __shfl(rootG, stG); posG = __shfl(posG, stG);
        int pSlot = fgP ? (posP + 1) : 0;
        int gSlot = fgG ? (posG + 1) : 0;
        slotPacked[g] = pSlot | (gSlot << 16);
        bool edge = (lr == 0) | (lr == 63) | (lane == 0) | (lane == 63);
        if (edge) {
            labP[g] = fgP ? (((r0 + (rootP >> 6)) << 9) + (c0 + (rootP & 63))) : SENT;
            labG[g] = fgG ? (((r0 + (rootG >> 6)) << 9) + (c0 + (rootG & 63))) : SENT;
        }
    }
}

__device__ __forceinline__ void processB(int* L, int i, int r, int c, int kind) {
    if (L[i] >= SENT) return;
    if (kind == 1) {            // c%64==0, c>0: w and nw cross the tile edge
        if (L[i - 1] < SENT) unite(L, i, i - 1);
        if (r > 0 && L[i - WW - 1] < SENT) unite(L, i, i - WW - 1);
    } else if (kind == 2) {     // c%64==63, c<511: ne crosses
        if (r > 0 && c < WW - 1 && L[i - WW + 1] < SENT) unite(L, i, i - WW + 1);
    } else {                    // r%64==0, r>0: n, nw, ne cross
        if (L[i - WW] < SENT) unite(L, i, i - WW);
        if (c > 0 && L[i - WW - 1] < SENT) unite(L, i, i - WW - 1);
        if (c < WW - 1 && L[i - WW + 1] < SENT) unite(L, i, i - WW + 1);
    }
}

// Cross-tile merges only: 21 boundary lines x 512 per image per mask.
__global__ void k_bmerge(int* __restrict__ labP, int* __restrict__ labG) {
    const int PER = 21 * 512;
    int idx = blockIdx.x * blockDim.x + threadIdx.x;
    if (idx >= NB * PER) return;
    int b = idx / PER, rem = idx % PER;
    int kind = rem / (7 * 512);
    int q = (rem % (7 * 512)) >> 9;
    int u = rem & 511;
    int r, c;
    if (kind == 0)      { r = TS * (q + 1); c = u; }
    else if (kind == 1) { c = TS * (q + 1); r = u; }
    else                { c = TS * q + 63;  r = u; }
    int i = (r << 9) | c;
    processB(labP + (b << 18), i, r, c, kind);
    processB(labG + (b << 18), i, r, c, kind);
}

// one block per (image, mask): filter tile-root candidates to true roots (in LDS),
// size-adaptive bitonic sort ascending, compact first KC.
__global__ void k_sortroots(const int* __restrict__ labP, const int* __restrict__ labG,
                            const int* __restrict__ candP, const int* __restrict__ candG,
                            const int* __restrict__ candCntP, const int* __restrict__ candCntG,
                            int* __restrict__ compP, int* __restrict__ compG,
                            int* __restrict__ ccntP, int* __restrict__ ccntG) {
    __shared__ int s[RCAP];
    __shared__ int lcnt;
    int b = blockIdx.x >> 1;
    int which = blockIdx.x & 1;
    const int* cand = which ? candG : candP;
    const int* L = (which ? labG : labP) + (b << 18);
    int nc = min((which ? candCntG : candCntP)[b], CCAP);
    if (threadIdx.x == 0) lcnt = 0;
    __syncthreads();
    for (int t = threadIdx.x; t < nc; t += TPB) {
        int i = cand[b * CCAP + t];
        if (L[i] == i) { int pos = atomicAdd(&lcnt, 1); if (pos < RCAP) s[pos] = i; }
    }
    __syncthreads();
    int n = min(lcnt, RCAP);
    int m = 1; while (m < n) m <<= 1;
    for (int t = n + threadIdx.x; t < m; t += TPB) s[t] = IMAX;
    __syncthreads();
    for (int k = 2; k <= m; k <<= 1) {
        for (int j = k >> 1; j > 0; j >>= 1) {
            for (int t = threadIdx.x; t < m; t += TPB) {
                int ixj = t ^ j;
                if (ixj > t) {
                    int a = s[t], bb = s[ixj];
                    bool up = ((t & k) == 0);
                    if ((a > bb) == up) { s[t] = bb; s[ixj] = a; }
                }
            }
            __syncthreads();
        }
    }
    int cc = min(n, KC);
    int* comp = which ? compG : compP;
    int* ccnt = which ? ccntG : ccntP;
    for (int t = threadIdx.x; t < KC; t += TPB)
        comp[b * KC + t] = (t < cc) ? s[t] : IMAX;
    if (threadIdx.x == 0) ccnt[b] = cc;
}

// Per-slot: chase tile-root to global root, map to compact id, aggregate stats.
__global__ void k_redux(const int* __restrict__ labP, const int* __restrict__ labG,
                        const int* __restrict__ candP, const int* __restrict__ candG,
                        const int* __restrict__ candCntP, const int* __restrict__ candCntG,
                        const int* __restrict__ compP, const int* __restrict__ compG,
                        const int* __restrict__ sAreaP, const int* __restrict__ sRP, const int* __restrict__ sCP, const int* __restrict__ sOvP,
                        const int* __restrict__ sAreaG, const int* __restrict__ sRG, const int* __restrict__ sCG, const int* __restrict__ sOvG,
                        int* __restrict__ pA, int* __restrict__ pR, int* __restrict__ pC, int* __restrict__ ovP,
                        int* __restrict__ gA, int* __restrict__ gR, int* __restrict__ gC, int* __restrict__ ovG,
                        int* __restrict__ slotCidP, int* __restrict__ slotCidG) {
    int chunk = blockIdx.x & ((CCAP / TPB) - 1);
    int side = (blockIdx.x >> 4) & 1;            // CCAP/TPB = 16
    int b = blockIdx.x >> 5;
    int slot = (chunk << 8) + threadIdx.x;
    const int* cand = side ? candG : candP;
    const int* L = (side ? labG : labP) + (b << 18);
    const int* comp = (side ? compG : compP) + b * KC;
    int n = min((side ? candCntG : candCntP)[b], CCAP);
    if (slot >= n) return;
    int rootPx = cand[b * CCAP + slot];
    int gr = chaseRoot(L, rootPx);
    int cid = bsearch_k(comp, gr);
    (side ? slotCidG : slotCidP)[b * CCAP + slot] = cid;
    if (cid >= 0) {
        int idx = b * KC + cid;
        int sidx = b * CCAP + slot;
        if (side) {
            atomicAdd(&gA[idx], sAreaG[sidx]);
            atomicAdd(&gR[idx], sRG[sidx]);
            atomicAdd(&gC[idx], sCG[sidx]);
            if (sOvG[sidx]) atomicOr(&ovG[idx], 1);
        } else {
            atomicAdd(&pA[idx], sAreaP[sidx]);
            atomicAdd(&pR[idx], sRP[sidx]);
            atomicAdd(&pC[idx], sCP[sidx]);
            if (sOvP[sidx]) atomicOr(&ovP[idx], 1);
        }
    }
}

// per-image: nearest gt centroid per pred region, region errors;
// then scatter per-cid values to per-slot tables (fused post-pass).
__global__ void k_match(const int* __restrict__ pA, const int* __restrict__ pR, const int* __restrict__ pC,
                        const int* __restrict__ gA, const int* __restrict__ gR, const int* __restrict__ gC,
                        const int* __restrict__ ovP, const int* __restrict__ ovG,
                        const int* __restrict__ ccntP, const int* __restrict__ ccntG,
                        const int* __restrict__ candCntP, const int* __restrict__ candCntG,
                        const int* __restrict__ slotCidP, const int* __restrict__ slotCidG,
                        float* __restrict__ vPs, float* __restrict__ vGs) {
    __shared__ float sA[KC], sR[KC], sC[KC];
    __shared__ float sEG[KC];
    __shared__ float sFPl[KC], sFGl[KC];
    int b = blockIdx.x;
    int t = threadIdx.x;                           // block = 512 = KC
    int ccg = ccntG[b], ccp = ccntP[b];
    {
        int a = gA[b * KC + t];
        float fa = (float)a;
        float d = fmaxf(fa, 1.0f);
        sA[t] = fa;
        sR[t] = (float)gR[b * KC + t] / d;
        sC[t] = (float)gC[b * KC + t] / d;
        sEG[t] = 0.0f;
    }
    __syncthreads();
    float e_eff = 0.0f;
    int nn = 0;
    if (t < ccp) {
        float pa = (float)pA[b * KC + t];
        float dd = fmaxf(pa, 1.0f);
        float pcr = (float)pR[b * KC + t] / dd;
        float pcc = (float)pC[b * KC + t] / dd;
        float best = INFINITY;
        for (int gi = 0; gi < ccg; gi++) {
            float dr = pcr - sR[gi], dc = pcc - sC[gi];
            float d2 = dr * dr + dc * dc;
            if (d2 < best) { best = d2; nn = gi; }  // first-min ties like argmin
        }
        if (ccg > 0 && ovP[b * KC + t]) {
            float ratio = 1.0f - sA[nn] / dd;
            e_eff = fminf(fabsf(1.0f - expf(ratio)), 1.0f);
        }
    }
    if (e_eff > 0.0f) atomicMax((int*)&sEG[nn], __float_as_int(e_eff));
    sFPl[t] = ovP[b * KC + t] ? e_eff : -1.0f;
    __syncthreads();
    sFGl[t] = ovG[b * KC + t] ? fmaxf(sEG[t], 0.0f) : -1.0f;
    __syncthreads();
    int nP = min(candCntP[b], CCAP), nG = min(candCntG[b], CCAP);
    for (int s2 = t; s2 < nP; s2 += KC) {
        int cid = slotCidP[b * CCAP + s2];
        vPs[b * CCAP + s2] = (cid >= 0) ? sFPl[cid] : -3.0f;   // -3 = fg w/o compact id
    }
    for (int s2 = t; s2 < nG; s2 += KC) {
        int cid = slotCidG[b * CCAP + s2];
        vGs[b * CCAP + s2] = (cid >= 0) ? sFGl[cid] : 0.0f;
    }
}

// per-pixel error rules + fused loss/metric reduction: pure table lookups
__global__ __launch_bounds__(TPB) void k_final(const float* __restrict__ in,
                        const int* __restrict__ slotPacked,
                        const float* __restrict__ vPs, const float* __restrict__ vGs,
                        const int* __restrict__ ccntG, double* __restrict__ acc) {
    __shared__ float pLm[4], pPe[4];
    __shared__ int pCnt[4];
    int b = blockIdx.x >> 7;            // 128 blocks per image
    int blk = blockIdx.x & 127;
    bool hasGt = ccntG[b] > 0;
    const float* vP = vPs + b * CCAP;
    const float* vG = vGs + b * CCAP;
    int i0 = (blk << 11) + threadIdx.x;
    float aLm = 0.0f, aPe = 0.0f;
    int aCnt = 0;
    #pragma unroll
    for (int k = 0; k < 8; k++) {
        int g = (b << 18) + i0 + (k << 8);
        int f = slotPacked[g];
        float x = in[g];
        if (!__any(f != 0)) continue;    // whole wave background
        int fp = f & 0xffff;
        int fg = (f >> 16) & 0xffff;
        float pe = 0.0f;
        if (fp) {
            if (!hasGt) pe = 1.0f;
            else {
                float v = vP[fp - 1];
                if (v > -2.5f) {                  // has compact id
                    if (v < 0.0f) pe = 1.0f;      // pred region w/o overlap
                    else if (!fg) pe = v;         // pred px, gt!=1
                }
            }
        }
        if (fg) {
            float vg = vG[fg - 1];
            if (!fp) pe = fmaxf(pe, fmaxf(vg, 0.0f));   // gt px, pred<1
            if (vg < 0.0f) pe = 1.0f;                    // gt region w/o overlap
        }
        if (pe != 0.0f) {
            float score = 1.0f / (1.0f + expf(-x));
            aLm += (1.0f / (1.0f + expf(-(score + 1.0f) * pe)) - 0.5f) * 2.0f;
            aPe += pe;
            aCnt++;
        }
    }
    for (int o = 32; o; o >>= 1) {
        aLm += __shfl_xor(aLm, o);
        aPe += __shfl_xor(aPe, o);
        aCnt += __shfl_xor(aCnt, o);
    }
    int wv = threadIdx.x >> 6, lane = threadIdx.x & 63;
    if (lane == 0) { pLm[wv] = aLm; pPe[wv] = aPe; pCnt[wv] = aCnt; }
    __syncthreads();
    if (threadIdx.x == 0) {
        double sl = 0, sp = 0; int sc = 0;
        for (int q = 0; q < 4; q++) { sl += pLm[q]; sp += pPe[q]; sc += pCnt[q]; }
        atomicAdd(&acc[0], sl);
        atomicAdd(&acc[1], sp);
        atomicAdd(&acc[2], (double)sc);
    }
}

__global__ void k_out(const double* __restrict__ acc, float* __restrict__ out) {
    out[0] = (float)(acc[0] / (double)PN);
    out[1] = (float)(1.0 - acc[1] / (double)PN);
    out[2] = (float)(1.0 - acc[1] / acc[2]);
}

extern "C" void kernel_launch(void* const* d_in, const int* in_sizes, int n_in,
                              void* d_out, int out_size, void* d_ws, size_t ws_size,
                              hipStream_t stream) {
    const float* in = (const float*)d_in[0];
    const float* tg = (const float*)d_in[1];
    // d_in[2] = epoch, unused by forward

    char* w = (char*)d_ws;
    size_t off = 0;
    int* labP = (int*)(w + off); off += (size_t)PN * 4;
    int* labG = (int*)(w + off); off += (size_t)PN * 4;
    int* slotPacked = (int*)(w + off); off += (size_t)PN * 4;
    int* candP = (int*)(w + off); off += (size_t)NB * CCAP * 4;
    int* candG = (int*)(w + off); off += (size_t)NB * CCAP * 4;
    int* slotCidP = (int*)(w + off); off += (size_t)NB * CCAP * 4;
    int* slotCidG = (int*)(w + off); off += (size_t)NB * CCAP * 4;
    float* vPs = (float*)(w + off); off += (size_t)NB * CCAP * 4;
    float* vGs = (float*)(w + off); off += (size_t)NB * CCAP * 4;
    int* compP = (int*)(w + off); off += (size_t)NB * KC * 4;
    int* compG = (int*)(w + off); off += (size_t)NB * KC * 4;
    size_t zoff = off;
    int* candCntP = (int*)(w + off); off += NB * 4;
    int* candCntG = (int*)(w + off); off += NB * 4;
    int* ccntP = (int*)(w + off); off += NB * 4;
    int* ccntG = (int*)(w + off); off += NB * 4;
    int* sAreaP = (int*)(w + off); off += (size_t)NB * CCAP * 4;
    int* sRP    = (int*)(w + off); off += (size_t)NB * CCAP * 4;
    int* sCP    = (int*)(w + off); off += (size_t)NB * CCAP * 4;
    int* sOvP   = (int*)(w + off); off += (size_t)NB * CCAP * 4;
    int* sAreaG = (int*)(w + off); off += (size_t)NB * CCAP * 4;
    int* sRG    = (int*)(w + off); off += (size_t)NB * CCAP * 4;
    int* sCG    = (int*)(w + off); off += (size_t)NB * CCAP * 4;
    int* sOvG   = (int*)(w + off); off += (size_t)NB * CCAP * 4;
    int* pA = (int*)(w + off); off += (size_t)NB * KC * 4;
    int* pR = (int*)(w + off); off += (size_t)NB * KC * 4;
    int* pC = (int*)(w + off); off += (size_t)NB * KC * 4;
    int* gA = (int*)(w + off); off += (size_t)NB * KC * 4;
    int* gR = (int*)(w + off); off += (size_t)NB * KC * 4;
    int* gC = (int*)(w + off); off += (size_t)NB * KC * 4;
    int* ovP = (int*)(w + off); off += (size_t)NB * KC * 4;
    int* ovG = (int*)(w + off); off += (size_t)NB * KC * 4;
    double* acc = (double*)(w + off); off += 4 * 8;
    size_t zend = off;

    // zero counters, slot stats, cid stats, accumulators (fresh every call)
    hipMemsetAsync(w + zoff, 0, zend - zoff, stream);

    k_local<<<NB * 64, TPB, 0, stream>>>(in, tg, labP, labG, slotPacked,
                                         candP, candG, candCntP, candCntG,
                                         sAreaP, sRP, sCP, sOvP,
                                         sAreaG, sRG, sCG, sOvG);
    {
        const int total = NB * 21 * 512;
        k_bmerge<<<(total + TPB - 1) / TPB, TPB, 0, stream>>>(labP, labG);
    }
    k_sortroots<<<2 * NB, TPB, 0, stream>>>(labP, labG, candP, candG, candCntP, candCntG,
                                            compP, compG, ccntP, ccntG);
    k_redux<<<NB * 2 * (CCAP / TPB), TPB, 0, stream>>>(labP, labG, candP, candG,
                                                       candCntP, candCntG, compP, compG,
                                                       sAreaP, sRP, sCP, sOvP,
                                                       sAreaG, sRG, sCG, sOvG,
                                                       pA, pR, pC, ovP, gA, gR, gC, ovG,
                                                       slotCidP, slotCidG);
    k_match<<<NB, KC, 0, stream>>>(pA, pR, pC, gA, gR, gC, ovP, ovG, ccntP, ccntG,
                                   candCntP, candCntG, slotCidP, slotCidG, vPs, vGs);
    k_final<<<NB * 128, TPB, 0, stream>>>(in, slotPacked, vPs, vGs, ccntG, acc);
    k_out<<<1, 1, 0, stream>>>(acc, (float*)d_out);
}

// Round 8
// 215.817 us; speedup vs baseline: 1.1596x; 1.1596x over previous
//
#include <hip/hip_runtime.h>

#define NB 16
#define HH 512
#define WW 512
#define HWN (HH * WW)            // 262144 = 1<<18
#define SENT HWN                  // background sentinel
#define KC 512                    // max regions kept per image
#define RCAP 4096                 // root list capacity per image
#define CCAP 4096                 // tile-root slot capacity per image
#define PN (NB * HWN)
#define TPB 256
#define IMAX 0x7FFFFFFF
#define TS 64                     // CCL tile side
#define TSQ (TS * TS)             // 4096, local sentinel

// ---------------- union-find helpers (global mem) ----------------
__device__ __forceinline__ int findRoot(int* L, int i) {
    int p = L[i];
    while (p != i) { i = p; p = L[i]; }
    return i;
}

__device__ __forceinline__ int chaseRoot(const int* __restrict__ L, int i) {
    int p = L[i];
    while (p != i) { i = p; p = L[i]; }
    return i;
}

__device__ __forceinline__ void unite(int* L, int a, int b) {
    int ra = findRoot(L, a);
    int rb = findRoot(L, b);
    while (ra != rb) {
        int lo = min(ra, rb), hi = max(ra, rb);
        int old = atomicMin(&L[hi], lo);
        if (old == hi) return;
        ra = old; rb = lo;
    }
}

// ---------------- union-find helpers (LDS) ----------------
__device__ __forceinline__ int findRootL(int* s, int i) {
    int p = s[i];
    while (p != i) { i = p; p = s[i]; }
    return i;
}

__device__ __forceinline__ void uniteL(int* s, int a, int b) {
    int ra = findRootL(s, a);
    int rb = findRootL(s, b);
    while (ra != rb) {
        int lo = min(ra, rb), hi = max(ra, rb);
        int old = atomicMin(&s[hi], lo);
        if (old == hi) return;
        ra = old; rb = lo;
    }
}

// binary search exact key in ascending array of KC ints (padded IMAX)
__device__ __forceinline__ int bsearch_k(const int* a, int key) {
    int lo = 0, hi = KC;
    while (lo < hi) { int m = (lo + hi) >> 1; if (a[m] < key) lo = m + 1; else hi = m; }
    return (lo < KC && a[lo] == key) ? lo : -1;
}

// ---------------- kernels ----------------
// Per-tile CCL (round-6 structure): run-based labels (ballot), reduced union
// rules, per-pixel parallel compression; slots for tile roots; run-level
// stats; packed per-pixel slot write; labels only for root + edge pixels.
__global__ __launch_bounds__(TPB) void k_local(const float* __restrict__ in, const float* __restrict__ tg,
                        int* __restrict__ labP, int* __restrict__ labG,
                        int* __restrict__ slotPacked,
                        int* __restrict__ candP, int* __restrict__ candG,
                        int* __restrict__ candCntP, int* __restrict__ candCntG,
                        int* __restrict__ sAreaP, int* __restrict__ sRP, int* __restrict__ sCP, int* __restrict__ sOvP,
                        int* __restrict__ sAreaG, int* __restrict__ sRG, int* __restrict__ sCG, int* __restrict__ sOvG) {
    __shared__ int sp[TSQ];
    __shared__ int sg[TSQ];
    __shared__ unsigned long long rmP[TS], rmG[TS];
    int b = blockIdx.x >> 6;            // 64 tiles per image (8x8)
    int tile = blockIdx.x & 63;
    int r0 = (tile >> 3) << 6, c0 = (tile & 7) << 6;
    int base = (b << 18) + (r0 << 9) + c0;
    int wv = threadIdx.x >> 6, lane = threadIdx.x & 63;

    // phase 1: load, ballot row masks, run-start initial labels (no atomics)
    #pragma unroll
    for (int k = 0; k < 16; k++) {
        int lr = wv + (k << 2);
        bool p = in[base + (lr << 9) + lane] > 0.0f;   // sigmoid(x)>0.5 <=> x>0
        bool q = tg[base + (lr << 9) + lane] > 0.5f;
        unsigned long long mp = __ballot(p);
        unsigned long long mq = __ballot(q);
        int t = (lr << 6) + lane;
        unsigned long long below = (lane == 0) ? 0ULL : ((~mp) & ((1ULL << lane) - 1ULL));
        int st = below ? (64 - __clzll(below)) : 0;
        sp[t] = p ? ((lr << 6) + st) : TSQ;
        below = (lane == 0) ? 0ULL : ((~mq) & ((1ULL << lane) - 1ULL));
        st = below ? (64 - __clzll(below)) : 0;
        sg[t] = q ? ((lr << 6) + st) : TSQ;
        if (lane == 0) { rmP[lr] = mp; rmG[lr] = mq; }
    }
    __syncthreads();

    // phase 2: inter-row unions, reduced rules
    for (int lr = wv; lr < TS; lr += 4) {
        if (lr == 0) continue;
        int t = (lr << 6) + lane;
        {
            unsigned long long m = rmP[lr], a = rmP[lr - 1];
            if ((m >> lane) & 1ULL) {
                bool N  = (a >> lane) & 1ULL;
                bool W  = lane > 0  && ((m >> (lane - 1)) & 1ULL);
                bool NW = lane > 0  && ((a >> (lane - 1)) & 1ULL);
                bool E  = lane < 63 && ((m >> (lane + 1)) & 1ULL);
                bool NE = lane < 63 && ((a >> (lane + 1)) & 1ULL);
                if (N) { if (!(W && NW)) uniteL(sp, t, t - TS); }
                else {
                    if (NW && !W) uniteL(sp, t, t - TS - 1);
                    if (NE && !E) uniteL(sp, t, t - TS + 1);
                }
            }
        }
        {
            unsigned long long m = rmG[lr], a = rmG[lr - 1];
            if ((m >> lane) & 1ULL) {
                bool N  = (a >> lane) & 1ULL;
                bool W  = lane > 0  && ((m >> (lane - 1)) & 1ULL);
                bool NW = lane > 0  && ((a >> (lane - 1)) & 1ULL);
                bool E  = lane < 63 && ((m >> (lane + 1)) & 1ULL);
                bool NE = lane < 63 && ((a >> (lane + 1)) & 1ULL);
                if (N) { if (!(W && NW)) uniteL(sg, t, t - TS); }
                else {
                    if (NW && !W) uniteL(sg, t, t - TS - 1);
                    if (NE && !E) uniteL(sg, t, t - TS + 1);
                }
            }
        }
    }
    __syncthreads();

    // phase 3a: full path compression (racy-but-monotone, safe)
    #pragma unroll
    for (int k = 0; k < 16; k++) {
        int t = ((wv + (k << 2)) << 6) + lane;
        if (sp[t] < TSQ) sp[t] = findRootL(sp, t);
        if (sg[t] < TSQ) sg[t] = findRootL(sg, t);
    }
    __syncthreads();

    // phase 3b: roots -> slots (encode negative), candidates, root labels
    #pragma unroll
    for (int k = 0; k < 16; k++) {
        int t = ((wv + (k << 2)) << 6) + lane;
        if (sp[t] == t) {
            int pos = atomicAdd(&candCntP[b], 1);
            if (pos >= CCAP) pos = CCAP - 1;
            int gl = ((r0 + (t >> 6)) << 9) + (c0 + (t & 63));
            candP[b * CCAP + pos] = gl;
            labP[(b << 18) + gl] = gl;
            sp[t] = -(pos + 2);
        }
        if (sg[t] == t) {
            int pos = atomicAdd(&candCntG[b], 1);
            if (pos >= CCAP) pos = CCAP - 1;
            int gl = ((r0 + (t >> 6)) << 9) + (c0 + (t & 63));
            candG[b * CCAP + pos] = gl;
            labG[(b << 18) + gl] = gl;
            sg[t] = -(pos + 2);
        }
    }
    __syncthreads();

    // phase 3c: per-pixel packed slot write + edge labels + per-run stats
    #pragma unroll
    for (int k = 0; k < 16; k++) {
        int lr = wv + (k << 2);
        int t = (lr << 6) + lane;
        int gli = ((r0 + lr) << 9) + (c0 + lane);
        int g = (b << 18) + gli;
        int vp = sp[t], vg = sg[t];
        int pSlot = 0, pRootT = -1;
        if (vp != TSQ) {
            if (vp < 0) { pRootT = t; pSlot = -vp - 1; }
            else        { pRootT = vp; pSlot = -sp[vp] - 1; }
        }
        int gSlot = 0, gRootT = -1;
        if (vg != TSQ) {
            if (vg < 0) { gRootT = t; gSlot = -vg - 1; }
            else        { gRootT = vg; gSlot = -sg[vg] - 1; }
        }
        slotPacked[g] = pSlot | (gSlot << 16);
        bool edge = (lr == 0) || (lr == 63) || (lane == 0) || (lane == 63);
        if (edge) {
            labP[g] = (pRootT >= 0) ? (((r0 + (pRootT >> 6)) << 9) + (c0 + (pRootT & 63))) : SENT;
            labG[g] = (gRootT >= 0) ? (((r0 + (gRootT >> 6)) << 9) + (c0 + (gRootT & 63))) : SENT;
        }
        // run stats (run-start lanes only)
        unsigned long long mp = rmP[lr], mq = rmG[lr];
        bool isP = (mp >> lane) & 1ULL;
        if (isP && (lane == 0 || !((mp >> (lane - 1)) & 1ULL))) {
            unsigned long long x = ~(mp >> lane);
            int len = x ? (__ffsll((long long)x) - 1) : (64 - lane);
            int slot = pSlot - 1;
            unsigned long long runbits = (len >= 64) ? ~0ULL : (((1ULL << len) - 1ULL) << lane);
            atomicAdd(&sAreaP[b * CCAP + slot], len);
            atomicAdd(&sRP[b * CCAP + slot], (r0 + lr) * len);
            atomicAdd(&sCP[b * CCAP + slot], len * (c0 + lane) + (len * (len - 1)) / 2);
            if (mq & runbits) atomicOr(&sOvP[b * CCAP + slot], 1);
        }
        bool isG = (mq >> lane) & 1ULL;
        if (isG && (lane == 0 || !((mq >> (lane - 1)) & 1ULL))) {
            unsigned long long x = ~(mq >> lane);
            int len = x ? (__ffsll((long long)x) - 1) : (64 - lane);
            int slot = gSlot - 1;
            unsigned long long runbits = (len >= 64) ? ~0ULL : (((1ULL << len) - 1ULL) << lane);
            atomicAdd(&sAreaG[b * CCAP + slot], len);
            atomicAdd(&sRG[b * CCAP + slot], (r0 + lr) * len);
            atomicAdd(&sCG[b * CCAP + slot], len * (c0 + lane) + (len * (len - 1)) / 2);
            if (mp & runbits) atomicOr(&sOvG[b * CCAP + slot], 1);
        }
    }
}

__device__ __forceinline__ void processB(int* L, int i, int r, int c, int kind) {
    if (L[i] >= SENT) return;
    if (kind == 1) {            // c%64==0, c>0: w and nw cross the tile edge
        if (L[i - 1] < SENT) unite(L, i, i - 1);
        if (r > 0 && L[i - WW - 1] < SENT) unite(L, i, i - WW - 1);
    } else if (kind == 2) {     // c%64==63, c<511: ne crosses
        if (r > 0 && c < WW - 1 && L[i - WW + 1] < SENT) unite(L, i, i - WW + 1);
    } else {                    // r%64==0, r>0: n, nw, ne cross
        if (L[i - WW] < SENT) unite(L, i, i - WW);
        if (c > 0 && L[i - WW - 1] < SENT) unite(L, i, i - WW - 1);
        if (c < WW - 1 && L[i - WW + 1] < SENT) unite(L, i, i - WW + 1);
    }
}

// Cross-tile merges only: 21 boundary lines x 512 per image per mask.
__global__ void k_bmerge(int* __restrict__ labP, int* __restrict__ labG) {
    const int PER = 21 * 512;
    int idx = blockIdx.x * blockDim.x + threadIdx.x;
    if (idx >= NB * PER) return;
    int b = idx / PER, rem = idx % PER;
    int kind = rem / (7 * 512);
    int q = (rem % (7 * 512)) >> 9;
    int u = rem & 511;
    int r, c;
    if (kind == 0)      { r = TS * (q + 1); c = u; }
    else if (kind == 1) { c = TS * (q + 1); r = u; }
    else                { c = TS * q + 63;  r = u; }
    int i = (r << 9) | c;
    processB(labP + (b << 18), i, r, c, kind);
    processB(labG + (b << 18), i, r, c, kind);
}

// One block per IMAGE (512 thr): filter+sort roots (both masks), slot->cid
// redux with LDS stats, centroid match, scatter per-slot value tables.
__global__ __launch_bounds__(512) void k_post(
        const int* __restrict__ labP, const int* __restrict__ labG,
        const int* __restrict__ candP, const int* __restrict__ candG,
        const int* __restrict__ candCntP, const int* __restrict__ candCntG,
        const int* __restrict__ sAreaP, const int* __restrict__ sRP, const int* __restrict__ sCP, const int* __restrict__ sOvP,
        const int* __restrict__ sAreaG, const int* __restrict__ sRG, const int* __restrict__ sCG, const int* __restrict__ sOvG,
        int* __restrict__ ccntG_g, float* __restrict__ vPs, float* __restrict__ vGs) {
    __shared__ int s[RCAP];                       // sort buffer, later cid store
    __shared__ int compL[2][KC];
    __shared__ int stA[2][KC], stR[2][KC], stC[2][KC], stOv[2][KC];
    __shared__ float gAf[KC], gRf[KC], gCf[KC], sEG[KC], sFPl[KC], sFGl[KC];
    __shared__ int lcnt, ccX[2];
    int b = blockIdx.x;
    int tid = threadIdx.x;

    // A: filter + sort candidates per side, build compact tables in LDS
    for (int side = 0; side < 2; side++) {
        const int* cand = side ? candG : candP;
        const int* L = (side ? labG : labP) + (b << 18);
        int nc = min((side ? candCntG : candCntP)[b], CCAP);
        if (tid == 0) lcnt = 0;
        __syncthreads();
        for (int t = tid; t < nc; t += 512) {
            int i = cand[b * CCAP + t];
            if (L[i] == i) { int pos = atomicAdd(&lcnt, 1); if (pos < RCAP) s[pos] = i; }
        }
        __syncthreads();
        int n = min(lcnt, RCAP);
        int m = 1; while (m < n) m <<= 1;
        for (int t = n + tid; t < m; t += 512) s[t] = IMAX;
        __syncthreads();
        for (int k = 2; k <= m; k <<= 1) {
            for (int j = k >> 1; j > 0; j >>= 1) {
                for (int t = tid; t < m; t += 512) {
                    int ixj = t ^ j;
                    if (ixj > t) {
                        int a = s[t], bb = s[ixj];
                        bool up = ((t & k) == 0);
                        if ((a > bb) == up) { s[t] = bb; s[ixj] = a; }
                    }
                }
                __syncthreads();
            }
        }
        int cc = min(n, KC);
        for (int t = tid; t < KC; t += 512)
            compL[side][t] = (t < cc) ? s[t] : IMAX;
        if (tid == 0) { ccX[side] = cc; if (side) ccntG_g[b] = cc; }
        __syncthreads();
    }

    // B: zero LDS cid stats
    for (int t = tid; t < KC; t += 512) {
        stA[0][t] = 0; stR[0][t] = 0; stC[0][t] = 0; stOv[0][t] = 0;
        stA[1][t] = 0; stR[1][t] = 0; stC[1][t] = 0; stOv[1][t] = 0;
    }
    __syncthreads();

    // C: per-slot chase + bsearch + aggregate into LDS cid stats
    short* cidS = (short*)s;
    for (int side = 0; side < 2; side++) {
        const int* cand = side ? candG : candP;
        const int* L = (side ? labG : labP) + (b << 18);
        const int* aA = side ? sAreaG : sAreaP;
        const int* aR = side ? sRG : sRP;
        const int* aC = side ? sCG : sCP;
        const int* aO = side ? sOvG : sOvP;
        int n = min((side ? candCntG : candCntP)[b], CCAP);
        for (int slot = tid; slot < n; slot += 512) {
            int gr = chaseRoot(L, cand[b * CCAP + slot]);
            int cid = bsearch_k(compL[side], gr);
            cidS[side * CCAP + slot] = (short)cid;
            if (cid >= 0) {
                int sidx = b * CCAP + slot;
                atomicAdd(&stA[side][cid], aA[sidx]);
                atomicAdd(&stR[side][cid], aR[sidx]);
                atomicAdd(&stC[side][cid], aC[sidx]);
                if (aO[sidx]) atomicOr(&stOv[side][cid], 1);
            }
        }
    }
    __syncthreads();

    // D: nearest gt centroid per pred region, region errors
    int t = tid;                                   // 512 == KC
    int ccg = ccX[1], ccp = ccX[0];
    {
        float fa = (float)stA[1][t];
        float d = fmaxf(fa, 1.0f);
        gAf[t] = fa;
        gRf[t] = (float)stR[1][t] / d;
        gCf[t] = (float)stC[1][t] / d;
        sEG[t] = 0.0f;
    }
    __syncthreads();
    float e_eff = 0.0f;
    int nn = 0;
    if (t < ccp) {
        float pa = (float)stA[0][t];
        float dd = fmaxf(pa, 1.0f);
        float pcr = (float)stR[0][t] / dd;
        float pcc = (float)stC[0][t] / dd;
        float best = INFINITY;
        for (int gi = 0; gi < ccg; gi++) {
            float dr = pcr - gRf[gi], dc = pcc - gCf[gi];
            float d2 = dr * dr + dc * dc;
            if (d2 < best) { best = d2; nn = gi; }  // first-min ties like argmin
        }
        if (ccg > 0 && stOv[0][t]) {
            float ratio = 1.0f - gAf[nn] / dd;
            e_eff = fminf(fabsf(1.0f - __expf(ratio)), 1.0f);
        }
    }
    if (e_eff > 0.0f) atomicMax((int*)&sEG[nn], __float_as_int(e_eff));
    sFPl[t] = stOv[0][t] ? e_eff : -1.0f;
    __syncthreads();
    sFGl[t] = stOv[1][t] ? fmaxf(sEG[t], 0.0f) : -1.0f;
    __syncthreads();

    // E: scatter per-slot value tables
    int nP = min(candCntP[b], CCAP), nG = min(candCntG[b], CCAP);
    for (int s2 = tid; s2 < nP; s2 += 512) {
        int cid = cidS[s2];
        vPs[b * CCAP + s2] = (cid >= 0) ? sFPl[cid] : -3.0f;   // -3 = fg w/o compact id
    }
    for (int s2 = tid; s2 < nG; s2 += 512) {
        int cid = cidS[CCAP + s2];
        vGs[b * CCAP + s2] = (cid >= 0) ? sFGl[cid] : 0.0f;
    }
}

// per-pixel error rules + fused loss/metric reduction: pure table lookups
__global__ __launch_bounds__(TPB) void k_final(const float* __restrict__ in,
                        const int* __restrict__ slotPacked,
                        const float* __restrict__ vPs, const float* __restrict__ vGs,
                        const int* __restrict__ ccntG, double* __restrict__ acc) {
    __shared__ float pLm[4], pPe[4];
    __shared__ int pCnt[4];
    int b = blockIdx.x >> 6;            // 64 blocks per image
    int blk = blockIdx.x & 63;
    bool hasGt = ccntG[b] > 0;
    const float* vP = vPs + b * CCAP;
    const float* vG = vGs + b * CCAP;
    int i0 = (blk << 12) + threadIdx.x;
    float aLm = 0.0f, aPe = 0.0f;
    int aCnt = 0;
    #pragma unroll
    for (int k = 0; k < 16; k++) {
        int g = (b << 18) + i0 + (k << 8);
        int f = slotPacked[g];
        if (!__any(f != 0)) continue;    // whole wave background
        int fp = f & 0xffff;
        int fg = (f >> 16) & 0xffff;
        float pe = 0.0f;
        if (fp) {
            if (!hasGt) pe = 1.0f;
            else {
                float v = vP[fp - 1];
                if (v > -2.5f) {                  // has compact id
                    if (v < 0.0f) pe = 1.0f;      // pred region w/o overlap
                    else if (!fg) pe = v;         // pred px, gt!=1
                }
            }
        }
        if (fg) {
            float vg = vG[fg - 1];
            if (!fp) pe = fmaxf(pe, fmaxf(vg, 0.0f));   // gt px, pred<1
            if (vg < 0.0f) pe = 1.0f;                    // gt region w/o overlap
        }
        if (pe != 0.0f) {
            float x = in[g];                              // only error pixels load x
            float score = 1.0f / (1.0f + __expf(-x));
            aLm += (1.0f / (1.0f + __expf(-(score + 1.0f) * pe)) - 0.5f) * 2.0f;
            aPe += pe;
            aCnt++;
        }
    }
    for (int o = 32; o; o >>= 1) {
        aLm += __shfl_xor(aLm, o);
        aPe += __shfl_xor(aPe, o);
        aCnt += __shfl_xor(aCnt, o);
    }
    int wv = threadIdx.x >> 6, lane = threadIdx.x & 63;
    if (lane == 0) { pLm[wv] = aLm; pPe[wv] = aPe; pCnt[wv] = aCnt; }
    __syncthreads();
    if (threadIdx.x == 0) {
        double sl = 0, sp = 0; int sc = 0;
        for (int q = 0; q < 4; q++) { sl += pLm[q]; sp += pPe[q]; sc += pCnt[q]; }
        atomicAdd(&acc[0], sl);
        atomicAdd(&acc[1], sp);
        atomicAdd(&acc[2], (double)sc);
    }
}

__global__ void k_out(const double* __restrict__ acc, float* __restrict__ out) {
    out[0] = (float)(acc[0] / (double)PN);
    out[1] = (float)(1.0 - acc[1] / (double)PN);
    out[2] = (float)(1.0 - acc[1] / acc[2]);
}

extern "C" void kernel_launch(void* const* d_in, const int* in_sizes, int n_in,
                              void* d_out, int out_size, void* d_ws, size_t ws_size,
                              hipStream_t stream) {
    const float* in = (const float*)d_in[0];
    const float* tg = (const float*)d_in[1];
    // d_in[2] = epoch, unused by forward

    char* w = (char*)d_ws;
    size_t off = 0;
    int* labP = (int*)(w + off); off += (size_t)PN * 4;
    int* labG = (int*)(w + off); off += (size_t)PN * 4;
    int* slotPacked = (int*)(w + off); off += (size_t)PN * 4;
    int* candP = (int*)(w + off); off += (size_t)NB * CCAP * 4;
    int* candG = (int*)(w + off); off += (size_t)NB * CCAP * 4;
    float* vPs = (float*)(w + off); off += (size_t)NB * CCAP * 4;
    float* vGs = (float*)(w + off); off += (size_t)NB * CCAP * 4;
    int* ccntG = (int*)(w + off); off += NB * 4;
    size_t zoff = off;
    int* candCntP = (int*)(w + off); off += NB * 4;
    int* candCntG = (int*)(w + off); off += NB * 4;
    int* sAreaP = (int*)(w + off); off += (size_t)NB * CCAP * 4;
    int* sRP    = (int*)(w + off); off += (size_t)NB * CCAP * 4;
    int* sCP    = (int*)(w + off); off += (size_t)NB * CCAP * 4;
    int* sOvP   = (int*)(w + off); off += (size_t)NB * CCAP * 4;
    int* sAreaG = (int*)(w + off); off += (size_t)NB * CCAP * 4;
    int* sRG    = (int*)(w + off); off += (size_t)NB * CCAP * 4;
    int* sCG    = (int*)(w + off); off += (size_t)NB * CCAP * 4;
    int* sOvG   = (int*)(w + off); off += (size_t)NB * CCAP * 4;
    double* acc = (double*)(w + off); off += 4 * 8;
    size_t zend = off;

    // zero counters, slot stats, accumulators (fresh every call)
    hipMemsetAsync(w + zoff, 0, zend - zoff, stream);

    k_local<<<NB * 64, TPB, 0, stream>>>(in, tg, labP, labG, slotPacked,
                                         candP, candG, candCntP, candCntG,
                                         sAreaP, sRP, sCP, sOvP,
                                         sAreaG, sRG, sCG, sOvG);
    {
        const int total = NB * 21 * 512;
        k_bmerge<<<(total + TPB - 1) / TPB, TPB, 0, stream>>>(labP, labG);
    }
    k_post<<<NB, 512, 0, stream>>>(labP, labG, candP, candG, candCntP, candCntG,
                                   sAreaP, sRP, sCP, sOvP,
                                   sAreaG, sRG, sCG, sOvG,
                                   ccntG, vPs, vGs);
    k_final<<<NB * 64, TPB, 0, stream>>>(in, slotPacked, vPs, vGs, ccntG, acc);
    k_out<<<1, 1, 0, stream>>>(acc, (float*)d_out);
}

// Round 9
// 204.227 us; speedup vs baseline: 1.2254x; 1.0568x over previous
//
#include <hip/hip_runtime.h>

#define NB 16
#define HH 512
#define WW 512
#define HWN (HH * WW)            // 262144 = 1<<18
#define SENT HWN                  // background sentinel
#define KC 512                    // max regions kept per image
#define RCAP 4096                 // root list capacity per image
#define CCAP 4096                 // tile-root slot capacity per image
#define PN (NB * HWN)
#define TPB 256
#define IMAX 0x7FFFFFFF
#define TS 64                     // CCL tile side
#define TSQ (TS * TS)             // 4096, local sentinel

typedef unsigned short ushortT;
typedef unsigned int uintT;

// ---------------- union-find helpers (global mem) ----------------
__device__ __forceinline__ int findRoot(int* L, int i) {
    int p = L[i];
    while (p != i) { i = p; p = L[i]; }
    return i;
}

__device__ __forceinline__ int chaseRoot(const int* __restrict__ L, int i) {
    int p = L[i];
    while (p != i) { i = p; p = L[i]; }
    return i;
}

__device__ __forceinline__ void unite(int* L, int a, int b) {
    int ra = findRoot(L, a);
    int rb = findRoot(L, b);
    while (ra != rb) {
        int lo = min(ra, rb), hi = max(ra, rb);
        int old = atomicMin(&L[hi], lo);
        if (old == hi) return;
        ra = old; rb = lo;
    }
}

// ---------------- union-find helpers (LDS) ----------------
__device__ __forceinline__ int findRootL(int* s, int i) {
    int p = s[i];
    while (p != i) { i = p; p = s[i]; }
    return i;
}

__device__ __forceinline__ void uniteL(int* s, int a, int b) {
    int ra = findRootL(s, a);
    int rb = findRootL(s, b);
    while (ra != rb) {
        int lo = min(ra, rb), hi = max(ra, rb);
        int old = atomicMin(&s[hi], lo);
        if (old == hi) return;
        ra = old; rb = lo;
    }
}

// binary search exact key in ascending array of KC ints (padded IMAX)
__device__ __forceinline__ int bsearch_k(const int* a, int key) {
    int lo = 0, hi = KC;
    while (lo < hi) { int m = (lo + hi) >> 1; if (a[m] < key) lo = m + 1; else hi = m; }
    return (lo < KC && a[lo] == key) ? lo : -1;
}

// ---------------- kernels ----------------
// Per-(tile,mask) CCL: one block per mask of one tile (grid 2x). 17KB LDS ->
// ~8 blocks/CU. Run-based labels (ballot), reduced union rules, per-pixel
// parallel compression; slots for tile roots; run-level stats (overlap via
// other-mask ballots); per-pixel ushort slot write; labels only root+edge.
__global__ __launch_bounds__(TPB) void k_local(const float* __restrict__ in, const float* __restrict__ tg,
                        int* __restrict__ labP, int* __restrict__ labG,
                        ushortT* __restrict__ slotP, ushortT* __restrict__ slotG,
                        int* __restrict__ candP, int* __restrict__ candG,
                        int* __restrict__ candCntP, int* __restrict__ candCntG,
                        int* __restrict__ sAreaP, int* __restrict__ sRP, int* __restrict__ sCP, int* __restrict__ sOvP,
                        int* __restrict__ sAreaG, int* __restrict__ sRG, int* __restrict__ sCG, int* __restrict__ sOvG) {
    __shared__ int s[TSQ];
    __shared__ unsigned long long rm[TS], rmO[TS];
    int side = blockIdx.x & 1;
    int tileIdx = blockIdx.x >> 1;
    int b = tileIdx >> 6;               // 64 tiles per image (8x8)
    int tile = tileIdx & 63;
    int r0 = (tile >> 3) << 6, c0 = (tile & 7) << 6;
    int base = (b << 18) + (r0 << 9) + c0;
    int wv = threadIdx.x >> 6, lane = threadIdx.x & 63;

    const float* own = side ? tg : in;
    const float* oth = side ? in : tg;
    const float ownThr = side ? 0.5f : 0.0f;   // gt: >0.5 ; pred: sigmoid>0.5 <=> x>0
    const float othThr = side ? 0.0f : 0.5f;
    int* lab = side ? labG : labP;
    ushortT* slotArr = side ? slotG : slotP;
    int* cand = side ? candG : candP;
    int* candCnt = side ? candCntG : candCntP;
    int* sArea = side ? sAreaG : sAreaP;
    int* sR = side ? sRG : sRP;
    int* sC = side ? sCG : sCP;
    int* sOv = side ? sOvG : sOvP;

    // phase 1: load both masks, ballot row masks, run-start labels
    #pragma unroll
    for (int k = 0; k < 16; k++) {
        int lr = wv + (k << 2);
        int gg = base + (lr << 9) + lane;
        bool p = own[gg] > ownThr;
        bool q = oth[gg] > othThr;
        unsigned long long mp = __ballot(p);
        unsigned long long mq = __ballot(q);
        int t = (lr << 6) + lane;
        unsigned long long below = (lane == 0) ? 0ULL : ((~mp) & ((1ULL << lane) - 1ULL));
        int st = below ? (64 - __clzll(below)) : 0;
        s[t] = p ? ((lr << 6) + st) : TSQ;
        if (lane == 0) { rm[lr] = mp; rmO[lr] = mq; }
    }
    __syncthreads();

    // phase 2: inter-row unions, reduced rules (one union per adjacent run-pair)
    for (int lr = wv; lr < TS; lr += 4) {
        if (lr == 0) continue;
        int t = (lr << 6) + lane;
        unsigned long long m = rm[lr], a = rm[lr - 1];
        if ((m >> lane) & 1ULL) {
            bool N  = (a >> lane) & 1ULL;
            bool W  = lane > 0  && ((m >> (lane - 1)) & 1ULL);
            bool NW = lane > 0  && ((a >> (lane - 1)) & 1ULL);
            bool E  = lane < 63 && ((m >> (lane + 1)) & 1ULL);
            bool NE = lane < 63 && ((a >> (lane + 1)) & 1ULL);
            if (N) { if (!(W && NW)) uniteL(s, t, t - TS); }
            else {
                if (NW && !W) uniteL(s, t, t - TS - 1);
                if (NE && !E) uniteL(s, t, t - TS + 1);
            }
        }
    }
    __syncthreads();

    // phase 3a: full path compression (racy-but-monotone, safe)
    #pragma unroll
    for (int k = 0; k < 16; k++) {
        int t = ((wv + (k << 2)) << 6) + lane;
        if (s[t] < TSQ) s[t] = findRootL(s, t);
    }
    __syncthreads();

    // phase 3b: roots -> slots (encode negative), candidates, root labels
    #pragma unroll
    for (int k = 0; k < 16; k++) {
        int t = ((wv + (k << 2)) << 6) + lane;
        if (s[t] == t) {
            int pos = atomicAdd(&candCnt[b], 1);
            if (pos >= CCAP) pos = CCAP - 1;
            int gl = ((r0 + (t >> 6)) << 9) + (c0 + (t & 63));
            cand[b * CCAP + pos] = gl;
            lab[(b << 18) + gl] = gl;
            s[t] = -(pos + 2);
        }
    }
    __syncthreads();

    // phase 3c: per-pixel slot write + edge labels + per-run stats
    #pragma unroll
    for (int k = 0; k < 16; k++) {
        int lr = wv + (k << 2);
        int t = (lr << 6) + lane;
        int gli = ((r0 + lr) << 9) + (c0 + lane);
        int g = (b << 18) + gli;
        int vp = s[t];
        int slot = 0, rootT = -1;
        if (vp != TSQ) {
            if (vp < 0) { rootT = t; slot = -vp - 1; }
            else        { rootT = vp; slot = -s[vp] - 1; }
        }
        slotArr[g] = (ushortT)slot;
        bool edge = (lr == 0) || (lr == 63) || (lane == 0) || (lane == 63);
        if (edge) {
            lab[g] = (rootT >= 0) ? (((r0 + (rootT >> 6)) << 9) + (c0 + (rootT & 63))) : SENT;
        }
        // run stats (run-start lanes only)
        unsigned long long mp = rm[lr], mq = rmO[lr];
        bool isF = (mp >> lane) & 1ULL;
        if (isF && (lane == 0 || !((mp >> (lane - 1)) & 1ULL))) {
            unsigned long long x = ~(mp >> lane);
            int len = x ? (__ffsll((long long)x) - 1) : (64 - lane);
            int sl = slot - 1;
            unsigned long long runbits = (len >= 64) ? ~0ULL : (((1ULL << len) - 1ULL) << lane);
            atomicAdd(&sArea[b * CCAP + sl], len);
            atomicAdd(&sR[b * CCAP + sl], (r0 + lr) * len);
            atomicAdd(&sC[b * CCAP + sl], len * (c0 + lane) + (len * (len - 1)) / 2);
            if (mq & runbits) atomicOr(&sOv[b * CCAP + sl], 1);
        }
    }
}

__device__ __forceinline__ void processB(int* L, int i, int r, int c, int kind) {
    if (L[i] >= SENT) return;
    if (kind == 1) {            // c%64==0, c>0: w and nw cross the tile edge
        if (L[i - 1] < SENT) unite(L, i, i - 1);
        if (r > 0 && L[i - WW - 1] < SENT) unite(L, i, i - WW - 1);
    } else if (kind == 2) {     // c%64==63, c<511: ne crosses
        if (r > 0 && c < WW - 1 && L[i - WW + 1] < SENT) unite(L, i, i - WW + 1);
    } else {                    // r%64==0, r>0: n, nw, ne cross
        if (L[i - WW] < SENT) unite(L, i, i - WW);
        if (c > 0 && L[i - WW - 1] < SENT) unite(L, i, i - WW - 1);
        if (c < WW - 1 && L[i - WW + 1] < SENT) unite(L, i, i - WW + 1);
    }
}

// Cross-tile merges only: 21 boundary lines x 512 per image per mask.
__global__ void k_bmerge(int* __restrict__ labP, int* __restrict__ labG) {
    const int PER = 21 * 512;
    int idx = blockIdx.x * blockDim.x + threadIdx.x;
    if (idx >= NB * PER) return;
    int b = idx / PER, rem = idx % PER;
    int kind = rem / (7 * 512);
    int q = (rem % (7 * 512)) >> 9;
    int u = rem & 511;
    int r, c;
    if (kind == 0)      { r = TS * (q + 1); c = u; }
    else if (kind == 1) { c = TS * (q + 1); r = u; }
    else                { c = TS * q + 63;  r = u; }
    int i = (r << 9) | c;
    processB(labP + (b << 18), i, r, c, kind);
    processB(labG + (b << 18), i, r, c, kind);
}

// One block per IMAGE (512 thr): filter+sort roots (both masks), slot->cid
// redux with LDS stats, centroid match, scatter per-slot value tables.
__global__ __launch_bounds__(512) void k_post(
        const int* __restrict__ labP, const int* __restrict__ labG,
        const int* __restrict__ candP, const int* __restrict__ candG,
        const int* __restrict__ candCntP, const int* __restrict__ candCntG,
        const int* __restrict__ sAreaP, const int* __restrict__ sRP, const int* __restrict__ sCP, const int* __restrict__ sOvP,
        const int* __restrict__ sAreaG, const int* __restrict__ sRG, const int* __restrict__ sCG, const int* __restrict__ sOvG,
        int* __restrict__ ccntG_g, float* __restrict__ vPs, float* __restrict__ vGs) {
    __shared__ int s[RCAP];                       // sort buffer, later cid store
    __shared__ int compL[2][KC];
    __shared__ int stA[2][KC], stR[2][KC], stC[2][KC], stOv[2][KC];
    __shared__ float gAf[KC], gRf[KC], gCf[KC], sEG[KC], sFPl[KC], sFGl[KC];
    __shared__ int lcnt, ccX[2];
    int b = blockIdx.x;
    int tid = threadIdx.x;

    // A: filter + sort candidates per side, build compact tables in LDS
    for (int side = 0; side < 2; side++) {
        const int* cand = side ? candG : candP;
        const int* L = (side ? labG : labP) + (b << 18);
        int nc = min((side ? candCntG : candCntP)[b], CCAP);
        if (tid == 0) lcnt = 0;
        __syncthreads();
        for (int t = tid; t < nc; t += 512) {
            int i = cand[b * CCAP + t];
            if (L[i] == i) { int pos = atomicAdd(&lcnt, 1); if (pos < RCAP) s[pos] = i; }
        }
        __syncthreads();
        int n = min(lcnt, RCAP);
        int m = 1; while (m < n) m <<= 1;
        for (int t = n + tid; t < m; t += 512) s[t] = IMAX;
        __syncthreads();
        for (int k = 2; k <= m; k <<= 1) {
            for (int j = k >> 1; j > 0; j >>= 1) {
                for (int t = tid; t < m; t += 512) {
                    int ixj = t ^ j;
                    if (ixj > t) {
                        int a = s[t], bb = s[ixj];
                        bool up = ((t & k) == 0);
                        if ((a > bb) == up) { s[t] = bb; s[ixj] = a; }
                    }
                }
                __syncthreads();
            }
        }
        int cc = min(n, KC);
        for (int t = tid; t < KC; t += 512)
            compL[side][t] = (t < cc) ? s[t] : IMAX;
        if (tid == 0) { ccX[side] = cc; if (side) ccntG_g[b] = cc; }
        __syncthreads();
    }

    // B: zero LDS cid stats
    for (int t = tid; t < KC; t += 512) {
        stA[0][t] = 0; stR[0][t] = 0; stC[0][t] = 0; stOv[0][t] = 0;
        stA[1][t] = 0; stR[1][t] = 0; stC[1][t] = 0; stOv[1][t] = 0;
    }
    __syncthreads();

    // C: per-slot chase + bsearch + aggregate into LDS cid stats
    short* cidS = (short*)s;
    for (int side = 0; side < 2; side++) {
        const int* cand = side ? candG : candP;
        const int* L = (side ? labG : labP) + (b << 18);
        const int* aA = side ? sAreaG : sAreaP;
        const int* aR = side ? sRG : sRP;
        const int* aC = side ? sCG : sCP;
        const int* aO = side ? sOvG : sOvP;
        int n = min((side ? candCntG : candCntP)[b], CCAP);
        for (int slot = tid; slot < n; slot += 512) {
            int gr = chaseRoot(L, cand[b * CCAP + slot]);
            int cid = bsearch_k(compL[side], gr);
            cidS[side * CCAP + slot] = (short)cid;
            if (cid >= 0) {
                int sidx = b * CCAP + slot;
                atomicAdd(&stA[side][cid], aA[sidx]);
                atomicAdd(&stR[side][cid], aR[sidx]);
                atomicAdd(&stC[side][cid], aC[sidx]);
                if (aO[sidx]) atomicOr(&stOv[side][cid], 1);
            }
        }
    }
    __syncthreads();

    // D: nearest gt centroid per pred region, region errors
    int t = tid;                                   // 512 == KC
    int ccg = ccX[1], ccp = ccX[0];
    {
        float fa = (float)stA[1][t];
        float d = fmaxf(fa, 1.0f);
        gAf[t] = fa;
        gRf[t] = (float)stR[1][t] / d;
        gCf[t] = (float)stC[1][t] / d;
        sEG[t] = 0.0f;
    }
    __syncthreads();
    float e_eff = 0.0f;
    int nn = 0;
    if (t < ccp) {
        float pa = (float)stA[0][t];
        float dd = fmaxf(pa, 1.0f);
        float pcr = (float)stR[0][t] / dd;
        float pcc = (float)stC[0][t] / dd;
        float best = INFINITY;
        for (int gi = 0; gi < ccg; gi++) {
            float dr = pcr - gRf[gi], dc = pcc - gCf[gi];
            float d2 = dr * dr + dc * dc;
            if (d2 < best) { best = d2; nn = gi; }  // first-min ties like argmin
        }
        if (ccg > 0 && stOv[0][t]) {
            float ratio = 1.0f - gAf[nn] / dd;
            e_eff = fminf(fabsf(1.0f - __expf(ratio)), 1.0f);
        }
    }
    if (e_eff > 0.0f) atomicMax((int*)&sEG[nn], __float_as_int(e_eff));
    sFPl[t] = stOv[0][t] ? e_eff : -1.0f;
    __syncthreads();
    sFGl[t] = stOv[1][t] ? fmaxf(sEG[t], 0.0f) : -1.0f;
    __syncthreads();

    // E: scatter per-slot value tables
    int nP = min(candCntP[b], CCAP), nG = min(candCntG[b], CCAP);
    for (int s2 = tid; s2 < nP; s2 += 512) {
        int cid = cidS[s2];
        vPs[b * CCAP + s2] = (cid >= 0) ? sFPl[cid] : -3.0f;   // -3 = fg w/o compact id
    }
    for (int s2 = tid; s2 < nG; s2 += 512) {
        int cid = cidS[CCAP + s2];
        vGs[b * CCAP + s2] = (cid >= 0) ? sFGl[cid] : 0.0f;
    }
}

// per-pixel error rules + fused loss/metric reduction: pure table lookups.
// 2 pixels per thread via uint pair loads of the ushort slot arrays.
__global__ __launch_bounds__(TPB) void k_final(const float* __restrict__ in,
                        const ushortT* __restrict__ slotP, const ushortT* __restrict__ slotG,
                        const float* __restrict__ vPs, const float* __restrict__ vGs,
                        const int* __restrict__ ccntG, double* __restrict__ acc) {
    __shared__ float pLm[4], pPe[4];
    __shared__ int pCnt[4];
    const uintT* sp2 = (const uintT*)slotP;
    const uintT* sg2 = (const uintT*)slotG;
    const float2* in2 = (const float2*)in;
    int b = blockIdx.x >> 6;            // 64 blocks per image, 2048 pairs each
    int blk = blockIdx.x & 63;
    bool hasGt = ccntG[b] > 0;
    const float* vP = vPs + b * CCAP;
    const float* vG = vGs + b * CCAP;
    float aLm = 0.0f, aPe = 0.0f;
    int aCnt = 0;
    #pragma unroll
    for (int k = 0; k < 8; k++) {
        int pidx = (b << 17) + (blk << 11) + (k << 8) + threadIdx.x;
        uintT up = sp2[pidx], ug = sg2[pidx];
        if (!__any(up | ug)) continue;   // whole wave background
        float pe0 = 0.0f, pe1 = 0.0f;
        {
            int fp = up & 0xffff, fg = ug & 0xffff;
            if (fp) {
                if (!hasGt) pe0 = 1.0f;
                else {
                    float v = vP[fp - 1];
                    if (v > -2.5f) { if (v < 0.0f) pe0 = 1.0f; else if (!fg) pe0 = v; }
                }
            }
            if (fg) {
                float vg = vG[fg - 1];
                if (!fp) pe0 = fmaxf(pe0, fmaxf(vg, 0.0f));
                if (vg < 0.0f) pe0 = 1.0f;
            }
        }
        {
            int fp = up >> 16, fg = ug >> 16;
            if (fp) {
                if (!hasGt) pe1 = 1.0f;
                else {
                    float v = vP[fp - 1];
                    if (v > -2.5f) { if (v < 0.0f) pe1 = 1.0f; else if (!fg) pe1 = v; }
                }
            }
            if (fg) {
                float vg = vG[fg - 1];
                if (!fp) pe1 = fmaxf(pe1, fmaxf(vg, 0.0f));
                if (vg < 0.0f) pe1 = 1.0f;
            }
        }
        if (pe0 != 0.0f || pe1 != 0.0f) {
            float2 x2 = in2[pidx];
            if (pe0 != 0.0f) {
                float score = 1.0f / (1.0f + __expf(-x2.x));
                aLm += (1.0f / (1.0f + __expf(-(score + 1.0f) * pe0)) - 0.5f) * 2.0f;
                aPe += pe0; aCnt++;
            }
            if (pe1 != 0.0f) {
                float score = 1.0f / (1.0f + __expf(-x2.y));
                aLm += (1.0f / (1.0f + __expf(-(score + 1.0f) * pe1)) - 0.5f) * 2.0f;
                aPe += pe1; aCnt++;
            }
        }
    }
    for (int o = 32; o; o >>= 1) {
        aLm += __shfl_xor(aLm, o);
        aPe += __shfl_xor(aPe, o);
        aCnt += __shfl_xor(aCnt, o);
    }
    int wv = threadIdx.x >> 6, lane = threadIdx.x & 63;
    if (lane == 0) { pLm[wv] = aLm; pPe[wv] = aPe; pCnt[wv] = aCnt; }
    __syncthreads();
    if (threadIdx.x == 0) {
        double sl = 0, sp = 0; int sc = 0;
        for (int q = 0; q < 4; q++) { sl += pLm[q]; sp += pPe[q]; sc += pCnt[q]; }
        atomicAdd(&acc[0], sl);
        atomicAdd(&acc[1], sp);
        atomicAdd(&acc[2], (double)sc);
    }
}

__global__ void k_out(const double* __restrict__ acc, float* __restrict__ out) {
    out[0] = (float)(acc[0] / (double)PN);
    out[1] = (float)(1.0 - acc[1] / (double)PN);
    out[2] = (float)(1.0 - acc[1] / acc[2]);
}

extern "C" void kernel_launch(void* const* d_in, const int* in_sizes, int n_in,
                              void* d_out, int out_size, void* d_ws, size_t ws_size,
                              hipStream_t stream) {
    const float* in = (const float*)d_in[0];
    const float* tg = (const float*)d_in[1];
    // d_in[2] = epoch, unused by forward

    char* w = (char*)d_ws;
    size_t off = 0;
    int* labP = (int*)(w + off); off += (size_t)PN * 4;
    int* labG = (int*)(w + off); off += (size_t)PN * 4;
    ushortT* slotP = (ushortT*)(w + off); off += (size_t)PN * 2;
    ushortT* slotG = (ushortT*)(w + off); off += (size_t)PN * 2;
    int* candP = (int*)(w + off); off += (size_t)NB * CCAP * 4;
    int* candG = (int*)(w + off); off += (size_t)NB * CCAP * 4;
    float* vPs = (float*)(w + off); off += (size_t)NB * CCAP * 4;
    float* vGs = (float*)(w + off); off += (size_t)NB * CCAP * 4;
    int* ccntG = (int*)(w + off); off += NB * 4;
    size_t zoff = off;
    int* candCntP = (int*)(w + off); off += NB * 4;
    int* candCntG = (int*)(w + off); off += NB * 4;
    int* sAreaP = (int*)(w + off); off += (size_t)NB * CCAP * 4;
    int* sRP    = (int*)(w + off); off += (size_t)NB * CCAP * 4;
    int* sCP    = (int*)(w + off); off += (size_t)NB * CCAP * 4;
    int* sOvP   = (int*)(w + off); off += (size_t)NB * CCAP * 4;
    int* sAreaG = (int*)(w + off); off += (size_t)NB * CCAP * 4;
    int* sRG    = (int*)(w + off); off += (size_t)NB * CCAP * 4;
    int* sCG    = (int*)(w + off); off += (size_t)NB * CCAP * 4;
    int* sOvG   = (int*)(w + off); off += (size_t)NB * CCAP * 4;
    double* acc = (double*)(w + off); off += 4 * 8;
    size_t zend = off;

    // zero counters, slot stats, accumulators (fresh every call)
    hipMemsetAsync(w + zoff, 0, zend - zoff, stream);

    k_local<<<NB * 64 * 2, TPB, 0, stream>>>(in, tg, labP, labG, slotP, slotG,
                                             candP, candG, candCntP, candCntG,
                                             sAreaP, sRP, sCP, sOvP,
                                             sAreaG, sRG, sCG, sOvG);
    {
        const int total = NB * 21 * 512;
        k_bmerge<<<(total + TPB - 1) / TPB, TPB, 0, stream>>>(labP, labG);
    }
    k_post<<<NB, 512, 0, stream>>>(labP, labG, candP, candG, candCntP, candCntG,
                                   sAreaP, sRP, sCP, sOvP,
                                   sAreaG, sRG, sCG, sOvG,
                                   ccntG, vPs, vGs);
    k_final<<<NB * 64, TPB, 0, stream>>>(in, slotP, slotG, vPs, vGs, ccntG, acc);
    k_out<<<1, 1, 0, stream>>>(acc, (float*)d_out);
}